// Round 16
// baseline (98.750 us; speedup 1.0000x reference)
//
#include <hip/hip_runtime.h>
#include <cstdint>

#define F_IN   8
#define HID    64
#define F_OUTD 8
#define RDIM   256
#define CDIM   4096
#define NSETS  3
#define NIND   4096
#define MDIM   4096
#define MAXL   64
#define GC     16
#define MPW    4
#define PREPB  1024      // prep_in blocks inside setup kernel
#define MLPB   1536      // mlp blocks inside mlp+buckets kernel

using short8 = __attribute__((ext_vector_type(8))) short;
using f32x4  = __attribute__((ext_vector_type(4))) float;

// hardware packed f32->bf16 (RNE), low word = a
__device__ inline unsigned int cvtpk(float a, float b) {
    unsigned int r;
    asm("v_cvt_pk_bf16_f32 %0, %1, %2" : "=v"(r) : "v"(a), "v"(b));
    return r;
}
// packed unsigned 16-bit max (== bf16 max for nonnegative values)
__device__ inline unsigned int pkmaxu(unsigned int a, unsigned int b) {
    unsigned int r;
    asm("v_pk_max_u16 %0, %1, %2" : "=v"(r) : "v"(a), "v"(b));
    return r;
}

// ---------------- fused setup: prep_in + inverse perms + weight prep ----------
// blocks [0,PREPB): in [F][R][C] f32 -> inT2 [C][R][F] bf16 (tiled transpose).
// blocks [PREPB, PREPB+144): inv[si][c0]=k; block PREPB also converts weights.
// BIAS-AS-FEATURE: w1bf col 24 = b1. w2 columns permuted by tau so layer-1's
// packed relu output (D-frag order) IS the layer-2 B-frag:
//   tau(32*hi + 8*q + e) = 32*hi + 16*(e>>2) + 4*q + (e&3)
__global__ __launch_bounds__(256)
void setup1(const float* __restrict__ in, unsigned short* __restrict__ inT2,
            const int* __restrict__ ind0, const int* __restrict__ ind1,
            const int* __restrict__ ind2,
            const float* __restrict__ w1, const float* __restrict__ b1,
            const float* __restrict__ w2,
            int* __restrict__ inv,
            unsigned short* __restrict__ w1bf, unsigned short* __restrict__ w2bf) {
    const int PADH = 264;                       // halfs per c-row (528B)
    __shared__ unsigned short tile[32 * PADH];
    int b = blockIdx.x;
    int t = threadIdx.x;
    if (b < PREPB) {
        int c0 = (b & 127) * 32, r0 = (b >> 7) * 32;
        int tx = t & 31, ty = t >> 5;
#pragma unroll
        for (int f = 0; f < 8; f += 2)
#pragma unroll
            for (int rr = 0; rr < 4; rr++) {
                int r = ty + rr * 8;
                float v0 = in[((size_t)f * RDIM + (r0 + r)) * CDIM + c0 + tx];
                float v1 = in[((size_t)(f + 1) * RDIM + (r0 + r)) * CDIM + c0 + tx];
                *(unsigned int*)&tile[tx * PADH + r * 8 + f] = cvtpk(v0, v1);
            }
        __syncthreads();
        int r = t & 31, cl = t >> 5;
#pragma unroll
        for (int cc = 0; cc < 4; cc++) {
            int c = cc * 8 + cl;
            uint4 v = *(const uint4*)&tile[c * PADH + r * 8];
            *(uint4*)(inT2 + (((size_t)(c0 + c) * RDIM) + (r0 + r)) * 8) = v;
        }
    } else {
        int b2 = b - PREPB;                     // 0..143
        int si = b2 >> 4, kb = b2 & 15;
        int k  = kb * 256 + t;
        int s_ = si / 3, i_ = si % 3;
        const int* ind = (i_ == 0 ? ind0 : (i_ == 1 ? ind1 : ind2)) + (size_t)s_ * NIND * 2;
        int c0 = ind[2 * k];
        inv[(size_t)si * NIND + c0] = k;
        if (b2 == 0) {
            for (int i = t; i < 64 * 32; i += 256) {
                int j = i >> 5, kk = i & 31;
                float v = (kk < 24) ? w1[j * 24 + kk] : (kk == 24 ? b1[j] : 0.f);
                w1bf[i] = (unsigned short)(cvtpk(v, 0.f) & 0xffff);
            }
            for (int i = t; i < 16 * 64; i += 256) {
                int f = i >> 6, kg = i & 63;
                int hi = kg >> 5, q = (kg >> 3) & 3, e = kg & 7;
                int j = (hi << 5) + ((e >> 2) << 4) + (q << 2) + (e & 3);   // tau
                w2bf[i] = (f < 8) ? (unsigned short)(cvtpk(w2[f * 64 + j], 0.f) & 0xffff) : 0;
            }
        }
    }
}

// ---------------- MFMA MLP -> dense d, with build_buckets folded in ----------
// blocks [0,MLPB): one wave per (s, half-of-r, group of MPW m); fully
// in-register. blocks [MLPB, MLPB+144): bucket-invert the scatter.
// waves_per_eu(2,2): CAP occupancy at 2 waves/EU so the allocator has a
// 256-VGPR budget -- stops it parking live fragments in AGPRs and paying
// v_accvgpr_read on every fmaxf/cvtpk input (R15: 110 dyn VALU/iter vs 37
// in source at VGPR_Count=32).
__global__ __launch_bounds__(256)
__attribute__((amdgpu_waves_per_eu(2, 2)))
void mlp_store(const unsigned short* __restrict__ inT2,
               const unsigned short* __restrict__ w1bf,
               const unsigned short* __restrict__ w2bf,
               const float* __restrict__ b2,
               const int* __restrict__ ind0, const int* __restrict__ ind1,
               const int* __restrict__ ind2, const int* __restrict__ mix,
               const int* __restrict__ inv,
               unsigned short* __restrict__ dbuf,
               int* __restrict__ mergecnt, int* __restrict__ mergelist) {
    int t = threadIdx.x;
    if (blockIdx.x >= MLPB) {                  // ---- build_buckets part ----
        int b2_ = blockIdx.x - MLPB;           // 0..143
        int si = b2_ >> 4;
        int m  = (b2_ & 15) * 256 + t;
        int s_ = si / 3, i_ = si % 3;
        const int* ind = (i_ == 0 ? ind0 : (i_ == 1 ? ind1 : ind2)) + (size_t)s_ * NIND * 2;
        int mi = mix[(size_t)si * MDIM + m];
        int c  = ind[2 * mi + 1];
        int slot = atomicAdd(&mergecnt[c], 1);
        if (slot < MAXL) mergelist[(size_t)c * MAXL + slot] = s_ * MDIM + m;
        return;
    }

    int wave = t >> 6, lane = t & 63;
    int lo = lane & 15, q = lane >> 4;

    int wid  = blockIdx.x * 4 + wave;    // 0..6143
    int mgrp = wid & 1023;
    int half = (wid >> 10) & 1;
    int s_   = wid >> 11;
    int m0   = mgrp * MPW;

    short8 A1[4], A2[2];
#pragma unroll
    for (int tt = 0; tt < 4; tt++)
        A1[tt] = *(const short8*)(w1bf + ((16 * tt + lo) << 5) + (q << 3));
#pragma unroll
    for (int kk = 0; kk < 2; kk++)
        A2[kk] = *(const short8*)(w2bf + (lo << 6) + (kk << 5) + (q << 3));

    f32x4 zeroC = {0.f, 0.f, 0.f, 0.f};
    f32x4 b2f;
#pragma unroll
    for (int rg = 0; rg < 4; rg++) {
        int f = 4 * q + rg;
        b2f[rg] = (f < 8) ? b2[f] : 0.f;
    }

    // batched index chase: 3 rounds of MPW independent loads
    int gq[MPW] = {0, 0, 0, 0};
    if (q < 3) {
        int si = s_ * 3 + q;
        const int* indq = (q == 0 ? ind0 : (q == 1 ? ind1 : ind2)) + (size_t)s_ * NIND * 2;
        int mi[MPW], kk[MPW];
#pragma unroll
        for (int u = 0; u < MPW; u++) mi[u] = mix[(size_t)si * MDIM + m0 + u];
#pragma unroll
        for (int u = 0; u < MPW; u++) kk[u] = inv[(size_t)si * NIND + mi[u]];
#pragma unroll
        for (int u = 0; u < MPW; u++) gq[u] = indq[2 * kk[u] + 1];
    }
    const unsigned short* srcs[MPW];
#pragma unroll
    for (int u = 0; u < MPW; u++)
        srcs[u] = inT2 + ((size_t)gq[u] * RDIM + half * 128 + lo) * 8;

    unsigned short* dst = dbuf + (size_t)(s_ * MDIM + m0) * 2048 + half * 1024 + lo * 8 + q * 4;

    union U { unsigned int u[4]; short8 s; };
    // q==3: constant bias-feature fragment {1.0bf16, 0 x7}
    const short8 one8 = {(short)0x3F80, 0, 0, 0, 0, 0, 0, 0};

    short8 Bcur = one8;
    if (q < 3) Bcur = *(const short8*)srcs[0];
#pragma unroll
    for (int it = 0; it < MPW * 8; it++) {
        const int u = it >> 3, j = it & 7;
        short8 Bnext = Bcur;
        if (it < MPW * 8 - 1 && q < 3)
            Bnext = *(const short8*)(srcs[(it + 1) >> 3] + ((it + 1) & 7) * 128);

        f32x4 a0 = __builtin_amdgcn_mfma_f32_16x16x32_bf16(A1[0], Bcur, zeroC, 0, 0, 0);
        f32x4 a1 = __builtin_amdgcn_mfma_f32_16x16x32_bf16(A1[1], Bcur, zeroC, 0, 0, 0);
        f32x4 a2 = __builtin_amdgcn_mfma_f32_16x16x32_bf16(A1[2], Bcur, zeroC, 0, 0, 0);
        f32x4 a3 = __builtin_amdgcn_mfma_f32_16x16x32_bf16(A1[3], Bcur, zeroC, 0, 0, 0);

        // relu (fmaxf: also NaN-squashing) + bf16 pack: result IS the layer-2
        // B fragment (tau-permuted w2)
        U ba, bb;
        ba.u[0] = cvtpk(fmaxf(a0[0], 0.f), fmaxf(a0[1], 0.f));
        ba.u[1] = cvtpk(fmaxf(a0[2], 0.f), fmaxf(a0[3], 0.f));
        ba.u[2] = cvtpk(fmaxf(a1[0], 0.f), fmaxf(a1[1], 0.f));
        ba.u[3] = cvtpk(fmaxf(a1[2], 0.f), fmaxf(a1[3], 0.f));
        bb.u[0] = cvtpk(fmaxf(a2[0], 0.f), fmaxf(a2[1], 0.f));
        bb.u[1] = cvtpk(fmaxf(a2[2], 0.f), fmaxf(a2[3], 0.f));
        bb.u[2] = cvtpk(fmaxf(a3[0], 0.f), fmaxf(a3[1], 0.f));
        bb.u[3] = cvtpk(fmaxf(a3[2], 0.f), fmaxf(a3[3], 0.f));

        f32x4 o = __builtin_amdgcn_mfma_f32_16x16x32_bf16(A2[0], ba.s, b2f, 0, 0, 0);
        o = __builtin_amdgcn_mfma_f32_16x16x32_bf16(A2[1], bb.s, o, 0, 0, 0);

        if (q < 2) {   // store d (clamped at 0; negatives never beat zeros baseline)
            uint2 ov;
            ov.x = cvtpk(fmaxf(o[0], 0.f), fmaxf(o[1], 0.f));
            ov.y = cvtpk(fmaxf(o[2], 0.f), fmaxf(o[3], 0.f));
            *(uint2*)(dst + (size_t)u * 2048 + j * 128) = ov;
        }
        Bcur = Bnext;
    }
}

// ---------------- gather-max per dest column -> d_out [f][r][c] directly ------
// grid (CDIM/GC, 2); 1024-thread block = 16 waves; wave w owns column c0+w for
// a 128-row half: rows rbase (acc A) and rbase+64 (acc B). Per entry the wave
// reads 2KB contiguous (two back-to-back 1KB wave reads).
__global__ __launch_bounds__(1024)
void gather_max_t(const unsigned short* __restrict__ dbuf, const int* __restrict__ mergecnt,
                  const int* __restrict__ mergelist, float* __restrict__ out) {
    __shared__ unsigned int ldsP[4][64][20];   // [f/2][rloc][c] packed bf16 pairs
    __shared__ int mlist[GC][MAXL];
    int t = threadIdx.x;
    int w = t >> 6, lane = t & 63;
    int c0 = blockIdx.x * GC;
    int c  = c0 + w;

    int n = mergecnt[c];
    n = n < 0 ? 0 : (n > MAXL ? MAXL : n);        // uniform across the wave
    if (lane < n) {
        int idx = mergelist[(size_t)c * MAXL + lane];
        idx = idx < 0 ? 0 : (idx >= NSETS * MDIM ? NSETS * MDIM - 1 : idx);
        mlist[w][lane] = idx;
    }
    __syncthreads();

    int rbase = blockIdx.y * 128 + lane;
    uint4 accA = make_uint4(0u, 0u, 0u, 0u);
    uint4 accB = make_uint4(0u, 0u, 0u, 0u);
    if (n > 0) {
        const unsigned short* bp = dbuf + ((size_t)mlist[w][0] * RDIM + rbase) * 8;
        uint4 pa = *(const uint4*)(bp);
        uint4 pb = *(const uint4*)(bp + 64 * 8);
        for (int e = 1; e < n; e++) {
            const unsigned short* bq = dbuf + ((size_t)mlist[w][e] * RDIM + rbase) * 8;
            uint4 qa = *(const uint4*)(bq);
            uint4 qb = *(const uint4*)(bq + 64 * 8);
            accA.x = pkmaxu(accA.x, pa.x); accA.y = pkmaxu(accA.y, pa.y);
            accA.z = pkmaxu(accA.z, pa.z); accA.w = pkmaxu(accA.w, pa.w);
            accB.x = pkmaxu(accB.x, pb.x); accB.y = pkmaxu(accB.y, pb.y);
            accB.z = pkmaxu(accB.z, pb.z); accB.w = pkmaxu(accB.w, pb.w);
            pa = qa; pb = qb;
        }
        accA.x = pkmaxu(accA.x, pa.x); accA.y = pkmaxu(accA.y, pa.y);
        accA.z = pkmaxu(accA.z, pa.z); accA.w = pkmaxu(accA.w, pa.w);
        accB.x = pkmaxu(accB.x, pb.x); accB.y = pkmaxu(accB.y, pb.y);
        accB.z = pkmaxu(accB.z, pb.z); accB.w = pkmaxu(accB.w, pb.w);
    }

    // two transpose/write phases (rows rbase.., then rbase+64..)
#pragma unroll
    for (int p = 0; p < 2; p++) {
        if (p) __syncthreads();             // prior read pass done before refill
        uint4 a = p ? accB : accA;
        ldsP[0][lane][w] = a.x;
        ldsP[1][lane][w] = a.y;
        ldsP[2][lane][w] = a.z;
        ldsP[3][lane][w] = a.w;
        __syncthreads();

        // one (f-pair, row, c-quad) per thread: 1024 = 4 * 64 * 4.
        // fmaxf(x,0) is identity on legit values (>=0), squashes NaN/neg.
        int f2 = t >> 8, rl = (t >> 2) & 63, cq = t & 3;
        uint4 v = *(const uint4*)&ldsP[f2][rl][cq * 4];
        float4 lo, hi;
        lo.x = fmaxf(__uint_as_float(v.x << 16), 0.f);
        hi.x = fmaxf(__uint_as_float(v.x & 0xffff0000u), 0.f);
        lo.y = fmaxf(__uint_as_float(v.y << 16), 0.f);
        hi.y = fmaxf(__uint_as_float(v.y & 0xffff0000u), 0.f);
        lo.z = fmaxf(__uint_as_float(v.z << 16), 0.f);
        hi.z = fmaxf(__uint_as_float(v.z & 0xffff0000u), 0.f);
        lo.w = fmaxf(__uint_as_float(v.w << 16), 0.f);
        hi.w = fmaxf(__uint_as_float(v.w & 0xffff0000u), 0.f);
        size_t rowoff = (size_t)blockIdx.y * 128 + p * 64 + rl;
        *(float4*)&out[((size_t)(2 * f2) * RDIM + rowoff) * CDIM + c0 + cq * 4] = lo;
        *(float4*)&out[((size_t)(2 * f2 + 1) * RDIM + rowoff) * CDIM + c0 + cq * 4] = hi;
    }
}

extern "C" void kernel_launch(void* const* d_in, const int* in_sizes, int n_in,
                              void* d_out, int out_size, void* d_ws, size_t ws_size,
                              hipStream_t stream) {
    const float* input = (const float*)d_in[0];
    const float* w1    = (const float*)d_in[1];
    const float* b1    = (const float*)d_in[2];
    const float* w2    = (const float*)d_in[3];
    const float* b2    = (const float*)d_in[4];
    const int*   ind0  = (const int*)d_in[5];
    const int*   ind1  = (const int*)d_in[6];
    const int*   ind2  = (const int*)d_in[7];
    const int*   mix   = (const int*)d_in[8];

    const size_t MiB = 1ull << 20;
    char* ws = (char*)d_ws;
    unsigned short* inT2 = (unsigned short*)ws;                    // 16 MiB
    unsigned short* dbuf = (unsigned short*)(ws + 16 * MiB);       // 48 MiB
    char* tail = ws + 64 * MiB;
    int* inv       = (int*)tail;                                   // 144 KiB
    int* mergecnt  = (int*)(tail + 147456);                        // 16 KiB
    int* mergelist = (int*)(tail + 147456 + 16384);                // 1 MiB
    unsigned short* w1bf = (unsigned short*)(tail + 147456 + 16384 + (size_t)CDIM * MAXL * 4);
    unsigned short* w2bf = w1bf + 64 * 32;

    hipMemsetAsync(mergecnt, 0, CDIM * sizeof(int), stream);       // graph-capturable
    setup1<<<PREPB + 144, 256, 0, stream>>>(input, inT2, ind0, ind1, ind2,
                                            w1, b1, w2, inv, w1bf, w2bf);
    mlp_store<<<MLPB + 144, 256, 0, stream>>>(inT2, w1bf, w2bf, b2,
                                              ind0, ind1, ind2, mix, inv, dbuf,
                                              mergecnt, mergelist);
    gather_max_t<<<dim3(CDIM / GC, 2), 1024, 0, stream>>>(dbuf, mergecnt, mergelist,
                                                          (float*)d_out);
}

// Round 17
// 89.818 us; speedup vs baseline: 1.0994x; 1.0994x over previous
//
#include <hip/hip_runtime.h>
#include <cstdint>

#define F_IN   8
#define HID    64
#define F_OUTD 8
#define RDIM   256
#define CDIM   4096
#define NSETS  3
#define NIND   4096
#define MDIM   4096
#define MAXL   64
#define GC     16
#define MPW    4
#define PREPB  1024      // prep_in blocks inside setup kernel
#define MLPB   1536      // mlp blocks inside mlp+buckets kernel

using short8 = __attribute__((ext_vector_type(8))) short;
using f32x4  = __attribute__((ext_vector_type(4))) float;

// hardware packed f32->bf16 (RNE), low word = a
__device__ inline unsigned int cvtpk(float a, float b) {
    unsigned int r;
    asm("v_cvt_pk_bf16_f32 %0, %1, %2" : "=v"(r) : "v"(a), "v"(b));
    return r;
}
// packed unsigned 16-bit max (== bf16 max for nonnegative values)
__device__ inline unsigned int pkmaxu(unsigned int a, unsigned int b) {
    unsigned int r;
    asm("v_pk_max_u16 %0, %1, %2" : "=v"(r) : "v"(a), "v"(b));
    return r;
}

// ---------------- fused setup: prep_in + inverse perms + weight prep ----------
// blocks [0,PREPB): in [F][R][C] f32 -> inT2 [C][R][F] bf16 (tiled transpose).
// blocks [PREPB, PREPB+144): inv[si][c0]=k; block PREPB also converts weights.
// BIAS-AS-FEATURE: w1bf col 24 = b1. w2 columns permuted by tau so layer-1's
// packed relu output (D-frag order) IS the layer-2 B-frag:
//   tau(32*hi + 8*q + e) = 32*hi + 16*(e>>2) + 4*q + (e&3)
__global__ __launch_bounds__(256)
void setup1(const float* __restrict__ in, unsigned short* __restrict__ inT2,
            const int* __restrict__ ind0, const int* __restrict__ ind1,
            const int* __restrict__ ind2,
            const float* __restrict__ w1, const float* __restrict__ b1,
            const float* __restrict__ w2,
            int* __restrict__ inv,
            unsigned short* __restrict__ w1bf, unsigned short* __restrict__ w2bf) {
    const int PADH = 264;                       // halfs per c-row (528B)
    __shared__ unsigned short tile[32 * PADH];
    int b = blockIdx.x;
    int t = threadIdx.x;
    if (b < PREPB) {
        int c0 = (b & 127) * 32, r0 = (b >> 7) * 32;
        int tx = t & 31, ty = t >> 5;
#pragma unroll
        for (int f = 0; f < 8; f += 2)
#pragma unroll
            for (int rr = 0; rr < 4; rr++) {
                int r = ty + rr * 8;
                float v0 = in[((size_t)f * RDIM + (r0 + r)) * CDIM + c0 + tx];
                float v1 = in[((size_t)(f + 1) * RDIM + (r0 + r)) * CDIM + c0 + tx];
                *(unsigned int*)&tile[tx * PADH + r * 8 + f] = cvtpk(v0, v1);
            }
        __syncthreads();
        int r = t & 31, cl = t >> 5;
#pragma unroll
        for (int cc = 0; cc < 4; cc++) {
            int c = cc * 8 + cl;
            uint4 v = *(const uint4*)&tile[c * PADH + r * 8];
            *(uint4*)(inT2 + (((size_t)(c0 + c) * RDIM) + (r0 + r)) * 8) = v;
        }
    } else {
        int b2 = b - PREPB;                     // 0..143
        int si = b2 >> 4, kb = b2 & 15;
        int k  = kb * 256 + t;
        int s_ = si / 3, i_ = si % 3;
        const int* ind = (i_ == 0 ? ind0 : (i_ == 1 ? ind1 : ind2)) + (size_t)s_ * NIND * 2;
        int c0 = ind[2 * k];
        inv[(size_t)si * NIND + c0] = k;
        if (b2 == 0) {
            for (int i = t; i < 64 * 32; i += 256) {
                int j = i >> 5, kk = i & 31;
                float v = (kk < 24) ? w1[j * 24 + kk] : (kk == 24 ? b1[j] : 0.f);
                w1bf[i] = (unsigned short)(cvtpk(v, 0.f) & 0xffff);
            }
            for (int i = t; i < 16 * 64; i += 256) {
                int f = i >> 6, kg = i & 63;
                int hi = kg >> 5, q = (kg >> 3) & 3, e = kg & 7;
                int j = (hi << 5) + ((e >> 2) << 4) + (q << 2) + (e & 3);   // tau
                w2bf[i] = (f < 8) ? (unsigned short)(cvtpk(w2[f * 64 + j], 0.f) & 0xffff) : 0;
            }
        }
    }
}

// ---------------- MFMA MLP -> dense d, with build_buckets folded in ----------
// blocks [0,MLPB): one wave per (s, half-of-r, group of MPW m); fully
// in-register. blocks [MLPB, MLPB+144): bucket-invert the scatter.
// waves_per_eu(4,4): 128-VGPR budget fits the full ~90-VGPR live set (no
// AGPR parking / v_accvgpr_read bloat of R15's VGPR=32 allocation) while
// keeping 4 waves/SIMD of latency hiding (R16's (2,2) lost TLP: 53 us).
__global__ __launch_bounds__(256)
__attribute__((amdgpu_waves_per_eu(4, 4)))
void mlp_store(const unsigned short* __restrict__ inT2,
               const unsigned short* __restrict__ w1bf,
               const unsigned short* __restrict__ w2bf,
               const float* __restrict__ b2,
               const int* __restrict__ ind0, const int* __restrict__ ind1,
               const int* __restrict__ ind2, const int* __restrict__ mix,
               const int* __restrict__ inv,
               unsigned short* __restrict__ dbuf,
               int* __restrict__ mergecnt, int* __restrict__ mergelist) {
    int t = threadIdx.x;
    if (blockIdx.x >= MLPB) {                  // ---- build_buckets part ----
        int b2_ = blockIdx.x - MLPB;           // 0..143
        int si = b2_ >> 4;
        int m  = (b2_ & 15) * 256 + t;
        int s_ = si / 3, i_ = si % 3;
        const int* ind = (i_ == 0 ? ind0 : (i_ == 1 ? ind1 : ind2)) + (size_t)s_ * NIND * 2;
        int mi = mix[(size_t)si * MDIM + m];
        int c  = ind[2 * mi + 1];
        int slot = atomicAdd(&mergecnt[c], 1);
        if (slot < MAXL) mergelist[(size_t)c * MAXL + slot] = s_ * MDIM + m;
        return;
    }

    int wave = t >> 6, lane = t & 63;
    int lo = lane & 15, q = lane >> 4;

    int wid  = blockIdx.x * 4 + wave;    // 0..6143
    int mgrp = wid & 1023;
    int half = (wid >> 10) & 1;
    int s_   = wid >> 11;
    int m0   = mgrp * MPW;

    short8 A1[4], A2[2];
#pragma unroll
    for (int tt = 0; tt < 4; tt++)
        A1[tt] = *(const short8*)(w1bf + ((16 * tt + lo) << 5) + (q << 3));
#pragma unroll
    for (int kk = 0; kk < 2; kk++)
        A2[kk] = *(const short8*)(w2bf + (lo << 6) + (kk << 5) + (q << 3));

    f32x4 zeroC = {0.f, 0.f, 0.f, 0.f};
    f32x4 b2f;
#pragma unroll
    for (int rg = 0; rg < 4; rg++) {
        int f = 4 * q + rg;
        b2f[rg] = (f < 8) ? b2[f] : 0.f;
    }

    // batched index chase: 3 rounds of MPW independent loads
    int gq[MPW] = {0, 0, 0, 0};
    if (q < 3) {
        int si = s_ * 3 + q;
        const int* indq = (q == 0 ? ind0 : (q == 1 ? ind1 : ind2)) + (size_t)s_ * NIND * 2;
        int mi[MPW], kk[MPW];
#pragma unroll
        for (int u = 0; u < MPW; u++) mi[u] = mix[(size_t)si * MDIM + m0 + u];
#pragma unroll
        for (int u = 0; u < MPW; u++) kk[u] = inv[(size_t)si * NIND + mi[u]];
#pragma unroll
        for (int u = 0; u < MPW; u++) gq[u] = indq[2 * kk[u] + 1];
    }
    const unsigned short* srcs[MPW];
#pragma unroll
    for (int u = 0; u < MPW; u++)
        srcs[u] = inT2 + ((size_t)gq[u] * RDIM + half * 128 + lo) * 8;

    unsigned short* dst = dbuf + (size_t)(s_ * MDIM + m0) * 2048 + half * 1024 + lo * 8 + q * 4;

    union U { unsigned int u[4]; short8 s; };
    // q==3: constant bias-feature fragment {1.0bf16, 0 x7}
    const short8 one8 = {(short)0x3F80, 0, 0, 0, 0, 0, 0, 0};

    short8 Bcur = one8;
    if (q < 3) Bcur = *(const short8*)srcs[0];
#pragma unroll
    for (int it = 0; it < MPW * 8; it++) {
        const int u = it >> 3, j = it & 7;
        short8 Bnext = Bcur;
        if (it < MPW * 8 - 1 && q < 3)
            Bnext = *(const short8*)(srcs[(it + 1) >> 3] + ((it + 1) & 7) * 128);

        f32x4 a0 = __builtin_amdgcn_mfma_f32_16x16x32_bf16(A1[0], Bcur, zeroC, 0, 0, 0);
        f32x4 a1 = __builtin_amdgcn_mfma_f32_16x16x32_bf16(A1[1], Bcur, zeroC, 0, 0, 0);
        f32x4 a2 = __builtin_amdgcn_mfma_f32_16x16x32_bf16(A1[2], Bcur, zeroC, 0, 0, 0);
        f32x4 a3 = __builtin_amdgcn_mfma_f32_16x16x32_bf16(A1[3], Bcur, zeroC, 0, 0, 0);

        // relu (fmaxf: also NaN-squashing) + bf16 pack: result IS the layer-2
        // B fragment (tau-permuted w2)
        U ba, bb;
        ba.u[0] = cvtpk(fmaxf(a0[0], 0.f), fmaxf(a0[1], 0.f));
        ba.u[1] = cvtpk(fmaxf(a0[2], 0.f), fmaxf(a0[3], 0.f));
        ba.u[2] = cvtpk(fmaxf(a1[0], 0.f), fmaxf(a1[1], 0.f));
        ba.u[3] = cvtpk(fmaxf(a1[2], 0.f), fmaxf(a1[3], 0.f));
        bb.u[0] = cvtpk(fmaxf(a2[0], 0.f), fmaxf(a2[1], 0.f));
        bb.u[1] = cvtpk(fmaxf(a2[2], 0.f), fmaxf(a2[3], 0.f));
        bb.u[2] = cvtpk(fmaxf(a3[0], 0.f), fmaxf(a3[1], 0.f));
        bb.u[3] = cvtpk(fmaxf(a3[2], 0.f), fmaxf(a3[3], 0.f));

        f32x4 o = __builtin_amdgcn_mfma_f32_16x16x32_bf16(A2[0], ba.s, b2f, 0, 0, 0);
        o = __builtin_amdgcn_mfma_f32_16x16x32_bf16(A2[1], bb.s, o, 0, 0, 0);

        if (q < 2) {   // store d (clamped at 0; negatives never beat zeros baseline)
            uint2 ov;
            ov.x = cvtpk(fmaxf(o[0], 0.f), fmaxf(o[1], 0.f));
            ov.y = cvtpk(fmaxf(o[2], 0.f), fmaxf(o[3], 0.f));
            *(uint2*)(dst + (size_t)u * 2048 + j * 128) = ov;
        }
        Bcur = Bnext;
    }
}

// ---------------- gather-max per dest column -> d_out [f][r][c] directly ------
// grid (CDIM/GC, 2); 1024-thread block = 16 waves; wave w owns column c0+w for
// a 128-row half: rows rbase (acc A) and rbase+64 (acc B). Per entry the wave
// reads 2KB contiguous (two back-to-back 1KB wave reads).
__global__ __launch_bounds__(1024)
void gather_max_t(const unsigned short* __restrict__ dbuf, const int* __restrict__ mergecnt,
                  const int* __restrict__ mergelist, float* __restrict__ out) {
    __shared__ unsigned int ldsP[4][64][20];   // [f/2][rloc][c] packed bf16 pairs
    __shared__ int mlist[GC][MAXL];
    int t = threadIdx.x;
    int w = t >> 6, lane = t & 63;
    int c0 = blockIdx.x * GC;
    int c  = c0 + w;

    int n = mergecnt[c];
    n = n < 0 ? 0 : (n > MAXL ? MAXL : n);        // uniform across the wave
    if (lane < n) {
        int idx = mergelist[(size_t)c * MAXL + lane];
        idx = idx < 0 ? 0 : (idx >= NSETS * MDIM ? NSETS * MDIM - 1 : idx);
        mlist[w][lane] = idx;
    }
    __syncthreads();

    int rbase = blockIdx.y * 128 + lane;
    uint4 accA = make_uint4(0u, 0u, 0u, 0u);
    uint4 accB = make_uint4(0u, 0u, 0u, 0u);
    if (n > 0) {
        const unsigned short* bp = dbuf + ((size_t)mlist[w][0] * RDIM + rbase) * 8;
        uint4 pa = *(const uint4*)(bp);
        uint4 pb = *(const uint4*)(bp + 64 * 8);
        for (int e = 1; e < n; e++) {
            const unsigned short* bq = dbuf + ((size_t)mlist[w][e] * RDIM + rbase) * 8;
            uint4 qa = *(const uint4*)(bq);
            uint4 qb = *(const uint4*)(bq + 64 * 8);
            accA.x = pkmaxu(accA.x, pa.x); accA.y = pkmaxu(accA.y, pa.y);
            accA.z = pkmaxu(accA.z, pa.z); accA.w = pkmaxu(accA.w, pa.w);
            accB.x = pkmaxu(accB.x, pb.x); accB.y = pkmaxu(accB.y, pb.y);
            accB.z = pkmaxu(accB.z, pb.z); accB.w = pkmaxu(accB.w, pb.w);
            pa = qa; pb = qb;
        }
        accA.x = pkmaxu(accA.x, pa.x); accA.y = pkmaxu(accA.y, pa.y);
        accA.z = pkmaxu(accA.z, pa.z); accA.w = pkmaxu(accA.w, pa.w);
        accB.x = pkmaxu(accB.x, pb.x); accB.y = pkmaxu(accB.y, pb.y);
        accB.z = pkmaxu(accB.z, pb.z); accB.w = pkmaxu(accB.w, pb.w);
    }

    // two transpose/write phases (rows rbase.., then rbase+64..)
#pragma unroll
    for (int p = 0; p < 2; p++) {
        if (p) __syncthreads();             // prior read pass done before refill
        uint4 a = p ? accB : accA;
        ldsP[0][lane][w] = a.x;
        ldsP[1][lane][w] = a.y;
        ldsP[2][lane][w] = a.z;
        ldsP[3][lane][w] = a.w;
        __syncthreads();

        // one (f-pair, row, c-quad) per thread: 1024 = 4 * 64 * 4.
        // fmaxf(x,0) is identity on legit values (>=0), squashes NaN/neg.
        int f2 = t >> 8, rl = (t >> 2) & 63, cq = t & 3;
        uint4 v = *(const uint4*)&ldsP[f2][rl][cq * 4];
        float4 lo, hi;
        lo.x = fmaxf(__uint_as_float(v.x << 16), 0.f);
        hi.x = fmaxf(__uint_as_float(v.x & 0xffff0000u), 0.f);
        lo.y = fmaxf(__uint_as_float(v.y << 16), 0.f);
        hi.y = fmaxf(__uint_as_float(v.y & 0xffff0000u), 0.f);
        lo.z = fmaxf(__uint_as_float(v.z << 16), 0.f);
        hi.z = fmaxf(__uint_as_float(v.z & 0xffff0000u), 0.f);
        lo.w = fmaxf(__uint_as_float(v.w << 16), 0.f);
        hi.w = fmaxf(__uint_as_float(v.w & 0xffff0000u), 0.f);
        size_t rowoff = (size_t)blockIdx.y * 128 + p * 64 + rl;
        *(float4*)&out[((size_t)(2 * f2) * RDIM + rowoff) * CDIM + c0 + cq * 4] = lo;
        *(float4*)&out[((size_t)(2 * f2 + 1) * RDIM + rowoff) * CDIM + c0 + cq * 4] = hi;
    }
}

extern "C" void kernel_launch(void* const* d_in, const int* in_sizes, int n_in,
                              void* d_out, int out_size, void* d_ws, size_t ws_size,
                              hipStream_t stream) {
    const float* input = (const float*)d_in[0];
    const float* w1    = (const float*)d_in[1];
    const float* b1    = (const float*)d_in[2];
    const float* w2    = (const float*)d_in[3];
    const float* b2    = (const float*)d_in[4];
    const int*   ind0  = (const int*)d_in[5];
    const int*   ind1  = (const int*)d_in[6];
    const int*   ind2  = (const int*)d_in[7];
    const int*   mix   = (const int*)d_in[8];

    const size_t MiB = 1ull << 20;
    char* ws = (char*)d_ws;
    unsigned short* inT2 = (unsigned short*)ws;                    // 16 MiB
    unsigned short* dbuf = (unsigned short*)(ws + 16 * MiB);       // 48 MiB
    char* tail = ws + 64 * MiB;
    int* inv       = (int*)tail;                                   // 144 KiB
    int* mergecnt  = (int*)(tail + 147456);                        // 16 KiB
    int* mergelist = (int*)(tail + 147456 + 16384);                // 1 MiB
    unsigned short* w1bf = (unsigned short*)(tail + 147456 + 16384 + (size_t)CDIM * MAXL * 4);
    unsigned short* w2bf = w1bf + 64 * 32;

    hipMemsetAsync(mergecnt, 0, CDIM * sizeof(int), stream);       // graph-capturable
    setup1<<<PREPB + 144, 256, 0, stream>>>(input, inT2, ind0, ind1, ind2,
                                            w1, b1, w2, inv, w1bf, w2bf);
    mlp_store<<<MLPB + 144, 256, 0, stream>>>(inT2, w1bf, w2bf, b2,
                                              ind0, ind1, ind2, mix, inv, dbuf,
                                              mergecnt, mergelist);
    gather_max_t<<<dim3(CDIM / GC, 2), 1024, 0, stream>>>(dbuf, mergecnt, mergelist,
                                                          (float*)d_out);
}

// Round 18
// 86.184 us; speedup vs baseline: 1.1458x; 1.0422x over previous
//
#include <hip/hip_runtime.h>
#include <cstdint>

#define F_IN   8
#define HID    64
#define F_OUTD 8
#define RDIM   256
#define CDIM   4096
#define NSETS  3
#define NIND   4096
#define MDIM   4096
#define MAXL   64
#define GC     16
#define MPW    4
#define PREPB  1024      // prep_in blocks inside setup kernel
#define MLPB   1536      // mlp blocks inside mlp+buckets kernel

using short8 = __attribute__((ext_vector_type(8))) short;
using f32x4  = __attribute__((ext_vector_type(4))) float;

// hardware packed f32->bf16 (RNE), low word = a
__device__ inline unsigned int cvtpk(float a, float b) {
    unsigned int r;
    asm("v_cvt_pk_bf16_f32 %0, %1, %2" : "=v"(r) : "v"(a), "v"(b));
    return r;
}
// packed unsigned 16-bit max (== bf16 max for nonnegative values)
__device__ inline unsigned int pkmaxu(unsigned int a, unsigned int b) {
    unsigned int r;
    asm("v_pk_max_u16 %0, %1, %2" : "=v"(r) : "v"(a), "v"(b));
    return r;
}

// ---------------- fused setup: prep_in + inverse perms + weight prep ----------
// blocks [0,PREPB): in [F][R][C] f32 -> inT2 [C][R][F] bf16 (tiled transpose).
// blocks [PREPB, PREPB+144): inv[si][c0]=k; block PREPB also converts weights.
// BIAS-AS-FEATURE: w1bf col 24 = b1. w2 columns permuted by tau so layer-1's
// packed relu output (D-frag order) IS the layer-2 B-frag:
//   tau(32*hi + 8*q + e) = 32*hi + 16*(e>>2) + 4*q + (e&3)
__global__ __launch_bounds__(256)
void setup1(const float* __restrict__ in, unsigned short* __restrict__ inT2,
            const int* __restrict__ ind0, const int* __restrict__ ind1,
            const int* __restrict__ ind2,
            const float* __restrict__ w1, const float* __restrict__ b1,
            const float* __restrict__ w2,
            int* __restrict__ inv,
            unsigned short* __restrict__ w1bf, unsigned short* __restrict__ w2bf) {
    const int PADH = 264;                       // halfs per c-row (528B)
    __shared__ unsigned short tile[32 * PADH];
    int b = blockIdx.x;
    int t = threadIdx.x;
    if (b < PREPB) {
        int c0 = (b & 127) * 32, r0 = (b >> 7) * 32;
        int tx = t & 31, ty = t >> 5;
#pragma unroll
        for (int f = 0; f < 8; f += 2)
#pragma unroll
            for (int rr = 0; rr < 4; rr++) {
                int r = ty + rr * 8;
                float v0 = in[((size_t)f * RDIM + (r0 + r)) * CDIM + c0 + tx];
                float v1 = in[((size_t)(f + 1) * RDIM + (r0 + r)) * CDIM + c0 + tx];
                *(unsigned int*)&tile[tx * PADH + r * 8 + f] = cvtpk(v0, v1);
            }
        __syncthreads();
        int r = t & 31, cl = t >> 5;
#pragma unroll
        for (int cc = 0; cc < 4; cc++) {
            int c = cc * 8 + cl;
            uint4 v = *(const uint4*)&tile[c * PADH + r * 8];
            *(uint4*)(inT2 + (((size_t)(c0 + c) * RDIM) + (r0 + r)) * 8) = v;
        }
    } else {
        int b2 = b - PREPB;                     // 0..143
        int si = b2 >> 4, kb = b2 & 15;
        int k  = kb * 256 + t;
        int s_ = si / 3, i_ = si % 3;
        const int* ind = (i_ == 0 ? ind0 : (i_ == 1 ? ind1 : ind2)) + (size_t)s_ * NIND * 2;
        int c0 = ind[2 * k];
        inv[(size_t)si * NIND + c0] = k;
        if (b2 == 0) {
            for (int i = t; i < 64 * 32; i += 256) {
                int j = i >> 5, kk = i & 31;
                float v = (kk < 24) ? w1[j * 24 + kk] : (kk == 24 ? b1[j] : 0.f);
                w1bf[i] = (unsigned short)(cvtpk(v, 0.f) & 0xffff);
            }
            for (int i = t; i < 16 * 64; i += 256) {
                int f = i >> 6, kg = i & 63;
                int hi = kg >> 5, q = (kg >> 3) & 3, e = kg & 7;
                int j = (hi << 5) + ((e >> 2) << 4) + (q << 2) + (e & 3);   // tau
                w2bf[i] = (f < 8) ? (unsigned short)(cvtpk(w2[f * 64 + j], 0.f) & 0xffff) : 0;
            }
        }
    }
}

// ---------------- MFMA MLP -> dense d, with build_buckets folded in ----------
// blocks [0,MLPB): one wave per (s, half-of-r, group of MPW m); fully
// in-register. blocks [MLPB, MLPB+144): bucket-invert the scatter.
// R17 bracketing showed max-occupancy (VGPR=32) beats any VGPR-rich variant:
// the kernel is LATENCY-bound on its random L3 reads. Fix: 4 B-fragments in
// flight (prefetch it+3) -- 3x the latency tolerance of the old 2-deep chain.
__global__ __launch_bounds__(256, 2)
void mlp_store(const unsigned short* __restrict__ inT2,
               const unsigned short* __restrict__ w1bf,
               const unsigned short* __restrict__ w2bf,
               const float* __restrict__ b2,
               const int* __restrict__ ind0, const int* __restrict__ ind1,
               const int* __restrict__ ind2, const int* __restrict__ mix,
               const int* __restrict__ inv,
               unsigned short* __restrict__ dbuf,
               int* __restrict__ mergecnt, int* __restrict__ mergelist) {
    int t = threadIdx.x;
    if (blockIdx.x >= MLPB) {                  // ---- build_buckets part ----
        int b2_ = blockIdx.x - MLPB;           // 0..143
        int si = b2_ >> 4;
        int m  = (b2_ & 15) * 256 + t;
        int s_ = si / 3, i_ = si % 3;
        const int* ind = (i_ == 0 ? ind0 : (i_ == 1 ? ind1 : ind2)) + (size_t)s_ * NIND * 2;
        int mi = mix[(size_t)si * MDIM + m];
        int c  = ind[2 * mi + 1];
        int slot = atomicAdd(&mergecnt[c], 1);
        if (slot < MAXL) mergelist[(size_t)c * MAXL + slot] = s_ * MDIM + m;
        return;
    }

    int wave = t >> 6, lane = t & 63;
    int lo = lane & 15, q = lane >> 4;

    int wid  = blockIdx.x * 4 + wave;    // 0..6143
    int mgrp = wid & 1023;
    int half = (wid >> 10) & 1;
    int s_   = wid >> 11;
    int m0   = mgrp * MPW;

    short8 A1[4], A2[2];
#pragma unroll
    for (int tt = 0; tt < 4; tt++)
        A1[tt] = *(const short8*)(w1bf + ((16 * tt + lo) << 5) + (q << 3));
#pragma unroll
    for (int kk = 0; kk < 2; kk++)
        A2[kk] = *(const short8*)(w2bf + (lo << 6) + (kk << 5) + (q << 3));

    f32x4 zeroC = {0.f, 0.f, 0.f, 0.f};
    f32x4 b2f;
#pragma unroll
    for (int rg = 0; rg < 4; rg++) {
        int f = 4 * q + rg;
        b2f[rg] = (f < 8) ? b2[f] : 0.f;
    }

    // batched index chase: 3 rounds of MPW independent loads
    int gq[MPW] = {0, 0, 0, 0};
    if (q < 3) {
        int si = s_ * 3 + q;
        const int* indq = (q == 0 ? ind0 : (q == 1 ? ind1 : ind2)) + (size_t)s_ * NIND * 2;
        int mi[MPW], kk[MPW];
#pragma unroll
        for (int u = 0; u < MPW; u++) mi[u] = mix[(size_t)si * MDIM + m0 + u];
#pragma unroll
        for (int u = 0; u < MPW; u++) kk[u] = inv[(size_t)si * NIND + mi[u]];
#pragma unroll
        for (int u = 0; u < MPW; u++) gq[u] = indq[2 * kk[u] + 1];
    }
    const unsigned short* srcs[MPW];
#pragma unroll
    for (int u = 0; u < MPW; u++)
        srcs[u] = inT2 + ((size_t)gq[u] * RDIM + half * 128 + lo) * 8;

    unsigned short* dst = dbuf + (size_t)(s_ * MDIM + m0) * 2048 + half * 1024 + lo * 8 + q * 4;

    union U { unsigned int u[4]; short8 s; };
    // q==3: constant bias-feature fragment {1.0bf16, 0 x7}
    const short8 one8 = {(short)0x3F80, 0, 0, 0, 0, 0, 0, 0};

    // 4 fragments in flight (iters it, it+1, it+2 preloaded; prefetch it+3)
    short8 B0 = one8, B1 = one8, B2 = one8;
    if (q < 3) {
        B0 = *(const short8*)(srcs[0]);
        B1 = *(const short8*)(srcs[0] + 128);
        B2 = *(const short8*)(srcs[0] + 256);
    }
#pragma unroll
    for (int it = 0; it < MPW * 8; it++) {
        const int u = it >> 3, j = it & 7;
        short8 Bn = B2;
        if (it < MPW * 8 - 3 && q < 3) {
            const int it3 = it + 3;
            Bn = *(const short8*)(srcs[it3 >> 3] + (it3 & 7) * 128);
        }

        f32x4 a0 = __builtin_amdgcn_mfma_f32_16x16x32_bf16(A1[0], B0, zeroC, 0, 0, 0);
        f32x4 a1 = __builtin_amdgcn_mfma_f32_16x16x32_bf16(A1[1], B0, zeroC, 0, 0, 0);
        f32x4 a2 = __builtin_amdgcn_mfma_f32_16x16x32_bf16(A1[2], B0, zeroC, 0, 0, 0);
        f32x4 a3 = __builtin_amdgcn_mfma_f32_16x16x32_bf16(A1[3], B0, zeroC, 0, 0, 0);

        // relu (fmaxf: also NaN-squashing) + bf16 pack: result IS the layer-2
        // B fragment (tau-permuted w2)
        U ba, bb;
        ba.u[0] = cvtpk(fmaxf(a0[0], 0.f), fmaxf(a0[1], 0.f));
        ba.u[1] = cvtpk(fmaxf(a0[2], 0.f), fmaxf(a0[3], 0.f));
        ba.u[2] = cvtpk(fmaxf(a1[0], 0.f), fmaxf(a1[1], 0.f));
        ba.u[3] = cvtpk(fmaxf(a1[2], 0.f), fmaxf(a1[3], 0.f));
        bb.u[0] = cvtpk(fmaxf(a2[0], 0.f), fmaxf(a2[1], 0.f));
        bb.u[1] = cvtpk(fmaxf(a2[2], 0.f), fmaxf(a2[3], 0.f));
        bb.u[2] = cvtpk(fmaxf(a3[0], 0.f), fmaxf(a3[1], 0.f));
        bb.u[3] = cvtpk(fmaxf(a3[2], 0.f), fmaxf(a3[3], 0.f));

        f32x4 o = __builtin_amdgcn_mfma_f32_16x16x32_bf16(A2[0], ba.s, b2f, 0, 0, 0);
        o = __builtin_amdgcn_mfma_f32_16x16x32_bf16(A2[1], bb.s, o, 0, 0, 0);

        if (q < 2) {   // store d (clamped at 0; negatives never beat zeros baseline)
            uint2 ov;
            ov.x = cvtpk(fmaxf(o[0], 0.f), fmaxf(o[1], 0.f));
            ov.y = cvtpk(fmaxf(o[2], 0.f), fmaxf(o[3], 0.f));
            *(uint2*)(dst + (size_t)u * 2048 + j * 128) = ov;
        }
        B0 = B1; B1 = B2; B2 = Bn;
    }
}

// ---------------- gather-max per dest column -> d_out [f][r][c] directly ------
// grid (CDIM/GC, 2); 1024-thread block = 16 waves; wave w owns column c0+w for
// a 128-row half: rows rbase (acc A) and rbase+64 (acc B). Per entry the wave
// reads 2KB contiguous. 3 entries in flight (prefetch e+2; mlist padded with
// 2 duplicate entries -- max is idempotent) to cover random-read latency.
__global__ __launch_bounds__(1024)
void gather_max_t(const unsigned short* __restrict__ dbuf, const int* __restrict__ mergecnt,
                  const int* __restrict__ mergelist, float* __restrict__ out) {
    __shared__ unsigned int ldsP[4][64][20];   // [f/2][rloc][c] packed bf16 pairs
    __shared__ int mlist[GC][MAXL + 2];
    int t = threadIdx.x;
    int w = t >> 6, lane = t & 63;
    int c0 = blockIdx.x * GC;
    int c  = c0 + w;

    int n = mergecnt[c];
    n = n < 0 ? 0 : (n > MAXL ? MAXL : n);        // uniform across the wave
    if (lane < n) {
        int idx = mergelist[(size_t)c * MAXL + lane];
        idx = idx < 0 ? 0 : (idx >= NSETS * MDIM ? NSETS * MDIM - 1 : idx);
        mlist[w][lane] = idx;
    }
    if (lane == 0 && n > 0) {                     // pad 2 dups (max-idempotent)
        int idx = mergelist[(size_t)c * MAXL + (n - 1)];
        idx = idx < 0 ? 0 : (idx >= NSETS * MDIM ? NSETS * MDIM - 1 : idx);
        mlist[w][n] = idx;
        mlist[w][n + 1] = idx;
    }
    __syncthreads();

    int rbase = blockIdx.y * 128 + lane;
    uint4 accA = make_uint4(0u, 0u, 0u, 0u);
    uint4 accB = make_uint4(0u, 0u, 0u, 0u);
    if (n > 0) {
        const unsigned short* bp = dbuf + ((size_t)mlist[w][0] * RDIM + rbase) * 8;
        const unsigned short* bq = dbuf + ((size_t)mlist[w][1] * RDIM + rbase) * 8;
        uint4 pa = *(const uint4*)(bp);
        uint4 pb = *(const uint4*)(bp + 64 * 8);
        uint4 qa = *(const uint4*)(bq);
        uint4 qb = *(const uint4*)(bq + 64 * 8);
        for (int e = 0; e < n; e++) {
            const unsigned short* br = dbuf + ((size_t)mlist[w][e + 2] * RDIM + rbase) * 8;
            uint4 ra = *(const uint4*)(br);
            uint4 rb = *(const uint4*)(br + 64 * 8);
            accA.x = pkmaxu(accA.x, pa.x); accA.y = pkmaxu(accA.y, pa.y);
            accA.z = pkmaxu(accA.z, pa.z); accA.w = pkmaxu(accA.w, pa.w);
            accB.x = pkmaxu(accB.x, pb.x); accB.y = pkmaxu(accB.y, pb.y);
            accB.z = pkmaxu(accB.z, pb.z); accB.w = pkmaxu(accB.w, pb.w);
            pa = qa; pb = qb; qa = ra; qb = rb;
        }
    }

    // two transpose/write phases (rows rbase.., then rbase+64..)
#pragma unroll
    for (int p = 0; p < 2; p++) {
        if (p) __syncthreads();             // prior read pass done before refill
        uint4 a = p ? accB : accA;
        ldsP[0][lane][w] = a.x;
        ldsP[1][lane][w] = a.y;
        ldsP[2][lane][w] = a.z;
        ldsP[3][lane][w] = a.w;
        __syncthreads();

        // one (f-pair, row, c-quad) per thread: 1024 = 4 * 64 * 4.
        // fmaxf(x,0) is identity on legit values (>=0), squashes NaN/neg.
        int f2 = t >> 8, rl = (t >> 2) & 63, cq = t & 3;
        uint4 v = *(const uint4*)&ldsP[f2][rl][cq * 4];
        float4 lo, hi;
        lo.x = fmaxf(__uint_as_float(v.x << 16), 0.f);
        hi.x = fmaxf(__uint_as_float(v.x & 0xffff0000u), 0.f);
        lo.y = fmaxf(__uint_as_float(v.y << 16), 0.f);
        hi.y = fmaxf(__uint_as_float(v.y & 0xffff0000u), 0.f);
        lo.z = fmaxf(__uint_as_float(v.z << 16), 0.f);
        hi.z = fmaxf(__uint_as_float(v.z & 0xffff0000u), 0.f);
        lo.w = fmaxf(__uint_as_float(v.w << 16), 0.f);
        hi.w = fmaxf(__uint_as_float(v.w & 0xffff0000u), 0.f);
        size_t rowoff = (size_t)blockIdx.y * 128 + p * 64 + rl;
        *(float4*)&out[((size_t)(2 * f2) * RDIM + rowoff) * CDIM + c0 + cq * 4] = lo;
        *(float4*)&out[((size_t)(2 * f2 + 1) * RDIM + rowoff) * CDIM + c0 + cq * 4] = hi;
    }
}

extern "C" void kernel_launch(void* const* d_in, const int* in_sizes, int n_in,
                              void* d_out, int out_size, void* d_ws, size_t ws_size,
                              hipStream_t stream) {
    const float* input = (const float*)d_in[0];
    const float* w1    = (const float*)d_in[1];
    const float* b1    = (const float*)d_in[2];
    const float* w2    = (const float*)d_in[3];
    const float* b2    = (const float*)d_in[4];
    const int*   ind0  = (const int*)d_in[5];
    const int*   ind1  = (const int*)d_in[6];
    const int*   ind2  = (const int*)d_in[7];
    const int*   mix   = (const int*)d_in[8];

    const size_t MiB = 1ull << 20;
    char* ws = (char*)d_ws;
    unsigned short* inT2 = (unsigned short*)ws;                    // 16 MiB
    unsigned short* dbuf = (unsigned short*)(ws + 16 * MiB);       // 48 MiB
    char* tail = ws + 64 * MiB;
    int* inv       = (int*)tail;                                   // 144 KiB
    int* mergecnt  = (int*)(tail + 147456);                        // 16 KiB
    int* mergelist = (int*)(tail + 147456 + 16384);                // 1 MiB
    unsigned short* w1bf = (unsigned short*)(tail + 147456 + 16384 + (size_t)CDIM * MAXL * 4);
    unsigned short* w2bf = w1bf + 64 * 32;

    hipMemsetAsync(mergecnt, 0, CDIM * sizeof(int), stream);       // graph-capturable
    setup1<<<PREPB + 144, 256, 0, stream>>>(input, inT2, ind0, ind1, ind2,
                                            w1, b1, w2, inv, w1bf, w2bf);
    mlp_store<<<MLPB + 144, 256, 0, stream>>>(inT2, w1bf, w2bf, b2,
                                              ind0, ind1, ind2, mix, inv, dbuf,
                                              mergecnt, mergelist);
    gather_max_t<<<dim3(CDIM / GC, 2), 1024, 0, stream>>>(dbuf, mergecnt, mergelist,
                                                          (float*)d_out);
}

// Round 19
// 85.675 us; speedup vs baseline: 1.1526x; 1.0059x over previous
//
#include <hip/hip_runtime.h>
#include <cstdint>

#define F_IN   8
#define HID    64
#define F_OUTD 8
#define RDIM   256
#define CDIM   4096
#define NSETS  3
#define NIND   4096
#define MDIM   4096
#define MAXL   64
#define GC     16
#define MPW    4
#define PREPB  1024      // prep_in blocks inside setup kernel
#define MLPB   1536      // mlp blocks inside mlp+buckets kernel

using short8 = __attribute__((ext_vector_type(8))) short;
using f32x4  = __attribute__((ext_vector_type(4))) float;

// hardware packed f32->bf16 (RNE), low word = a
__device__ inline unsigned int cvtpk(float a, float b) {
    unsigned int r;
    asm("v_cvt_pk_bf16_f32 %0, %1, %2" : "=v"(r) : "v"(a), "v"(b));
    return r;
}
// packed unsigned 16-bit max (== bf16 max for nonnegative values)
__device__ inline unsigned int pkmaxu(unsigned int a, unsigned int b) {
    unsigned int r;
    asm("v_pk_max_u16 %0, %1, %2" : "=v"(r) : "v"(a), "v"(b));
    return r;
}

// ---------------- fused setup: prep_in + inverse perms + weight prep ----------
// blocks [0,PREPB): in [F][R][C] f32 -> inT2 [C][R][F] bf16 (tiled transpose).
// blocks [PREPB, PREPB+144): inv[si][c0]=k; block PREPB also converts weights.
// BIAS-AS-FEATURE: w1bf col 24 = b1. w2 columns permuted by tau so layer-1's
// packed relu output (D-frag order) IS the layer-2 B-frag:
//   tau(32*hi + 8*q + e) = 32*hi + 16*(e>>2) + 4*q + (e&3)
__global__ __launch_bounds__(256)
void setup1(const float* __restrict__ in, unsigned short* __restrict__ inT2,
            const int* __restrict__ ind0, const int* __restrict__ ind1,
            const int* __restrict__ ind2,
            const float* __restrict__ w1, const float* __restrict__ b1,
            const float* __restrict__ w2,
            int* __restrict__ inv,
            unsigned short* __restrict__ w1bf, unsigned short* __restrict__ w2bf) {
    const int PADH = 264;                       // halfs per c-row (528B)
    __shared__ unsigned short tile[32 * PADH];
    int b = blockIdx.x;
    int t = threadIdx.x;
    if (b < PREPB) {
        int c0 = (b & 127) * 32, r0 = (b >> 7) * 32;
        int tx = t & 31, ty = t >> 5;
#pragma unroll
        for (int f = 0; f < 8; f += 2)
#pragma unroll
            for (int rr = 0; rr < 4; rr++) {
                int r = ty + rr * 8;
                float v0 = in[((size_t)f * RDIM + (r0 + r)) * CDIM + c0 + tx];
                float v1 = in[((size_t)(f + 1) * RDIM + (r0 + r)) * CDIM + c0 + tx];
                *(unsigned int*)&tile[tx * PADH + r * 8 + f] = cvtpk(v0, v1);
            }
        __syncthreads();
        int r = t & 31, cl = t >> 5;
#pragma unroll
        for (int cc = 0; cc < 4; cc++) {
            int c = cc * 8 + cl;
            uint4 v = *(const uint4*)&tile[c * PADH + r * 8];
            *(uint4*)(inT2 + (((size_t)(c0 + c) * RDIM) + (r0 + r)) * 8) = v;
        }
    } else {
        int b2 = b - PREPB;                     // 0..143
        int si = b2 >> 4, kb = b2 & 15;
        int k  = kb * 256 + t;
        int s_ = si / 3, i_ = si % 3;
        const int* ind = (i_ == 0 ? ind0 : (i_ == 1 ? ind1 : ind2)) + (size_t)s_ * NIND * 2;
        int c0 = ind[2 * k];
        inv[(size_t)si * NIND + c0] = k;
        if (b2 == 0) {
            for (int i = t; i < 64 * 32; i += 256) {
                int j = i >> 5, kk = i & 31;
                float v = (kk < 24) ? w1[j * 24 + kk] : (kk == 24 ? b1[j] : 0.f);
                w1bf[i] = (unsigned short)(cvtpk(v, 0.f) & 0xffff);
            }
            for (int i = t; i < 16 * 64; i += 256) {
                int f = i >> 6, kg = i & 63;
                int hi = kg >> 5, q = (kg >> 3) & 3, e = kg & 7;
                int j = (hi << 5) + ((e >> 2) << 4) + (q << 2) + (e & 3);   // tau
                w2bf[i] = (f < 8) ? (unsigned short)(cvtpk(w2[f * 64 + j], 0.f) & 0xffff) : 0;
            }
        }
    }
}

// ---------------- MFMA MLP -> dense d, with build_buckets folded in ----------
// blocks [0,MLPB): one wave per (s, half-of-r, group of MPW m); fully
// in-register (tau-permuted w2, bias-as-feature with constant {1,0,..} B-frag
// for q==3). blocks [MLPB, MLPB+144): bucket-invert the scatter into one
// merged per-column list. Max-occupancy allocation (VGPR=32) is the bracketed
// optimum: 8/4/2 waves-per-EU -> 40/44/53 us; prefetch depth 2 vs 4: neutral.
// The kernel runs at ~2.85 TB/s of random-2KB L3 traffic -- its ceiling.
__global__ __launch_bounds__(256, 2)
void mlp_store(const unsigned short* __restrict__ inT2,
               const unsigned short* __restrict__ w1bf,
               const unsigned short* __restrict__ w2bf,
               const float* __restrict__ b2,
               const int* __restrict__ ind0, const int* __restrict__ ind1,
               const int* __restrict__ ind2, const int* __restrict__ mix,
               const int* __restrict__ inv,
               unsigned short* __restrict__ dbuf,
               int* __restrict__ mergecnt, int* __restrict__ mergelist) {
    int t = threadIdx.x;
    if (blockIdx.x >= MLPB) {                  // ---- build_buckets part ----
        int b2_ = blockIdx.x - MLPB;           // 0..143
        int si = b2_ >> 4;
        int m  = (b2_ & 15) * 256 + t;
        int s_ = si / 3, i_ = si % 3;
        const int* ind = (i_ == 0 ? ind0 : (i_ == 1 ? ind1 : ind2)) + (size_t)s_ * NIND * 2;
        int mi = mix[(size_t)si * MDIM + m];
        int c  = ind[2 * mi + 1];
        int slot = atomicAdd(&mergecnt[c], 1);
        if (slot < MAXL) mergelist[(size_t)c * MAXL + slot] = s_ * MDIM + m;
        return;
    }

    int wave = t >> 6, lane = t & 63;
    int lo = lane & 15, q = lane >> 4;

    int wid  = blockIdx.x * 4 + wave;    // 0..6143
    int mgrp = wid & 1023;
    int half = (wid >> 10) & 1;
    int s_   = wid >> 11;
    int m0   = mgrp * MPW;

    short8 A1[4], A2[2];
#pragma unroll
    for (int tt = 0; tt < 4; tt++)
        A1[tt] = *(const short8*)(w1bf + ((16 * tt + lo) << 5) + (q << 3));
#pragma unroll
    for (int kk = 0; kk < 2; kk++)
        A2[kk] = *(const short8*)(w2bf + (lo << 6) + (kk << 5) + (q << 3));

    f32x4 zeroC = {0.f, 0.f, 0.f, 0.f};
    f32x4 b2f;
#pragma unroll
    for (int rg = 0; rg < 4; rg++) {
        int f = 4 * q + rg;
        b2f[rg] = (f < 8) ? b2[f] : 0.f;
    }

    // batched index chase: 3 rounds of MPW independent loads
    int gq[MPW] = {0, 0, 0, 0};
    if (q < 3) {
        int si = s_ * 3 + q;
        const int* indq = (q == 0 ? ind0 : (q == 1 ? ind1 : ind2)) + (size_t)s_ * NIND * 2;
        int mi[MPW], kk[MPW];
#pragma unroll
        for (int u = 0; u < MPW; u++) mi[u] = mix[(size_t)si * MDIM + m0 + u];
#pragma unroll
        for (int u = 0; u < MPW; u++) kk[u] = inv[(size_t)si * NIND + mi[u]];
#pragma unroll
        for (int u = 0; u < MPW; u++) gq[u] = indq[2 * kk[u] + 1];
    }
    const unsigned short* srcs[MPW];
#pragma unroll
    for (int u = 0; u < MPW; u++)
        srcs[u] = inT2 + ((size_t)gq[u] * RDIM + half * 128 + lo) * 8;

    unsigned short* dst = dbuf + (size_t)(s_ * MDIM + m0) * 2048 + half * 1024 + lo * 8 + q * 4;

    union U { unsigned int u[4]; short8 s; };
    // q==3: constant bias-feature fragment {1.0bf16, 0 x7}
    const short8 one8 = {(short)0x3F80, 0, 0, 0, 0, 0, 0, 0};

    short8 Bcur = one8;
    if (q < 3) Bcur = *(const short8*)srcs[0];
#pragma unroll
    for (int it = 0; it < MPW * 8; it++) {
        const int u = it >> 3, j = it & 7;
        short8 Bnext = Bcur;
        if (it < MPW * 8 - 1 && q < 3)
            Bnext = *(const short8*)(srcs[(it + 1) >> 3] + ((it + 1) & 7) * 128);

        f32x4 a0 = __builtin_amdgcn_mfma_f32_16x16x32_bf16(A1[0], Bcur, zeroC, 0, 0, 0);
        f32x4 a1 = __builtin_amdgcn_mfma_f32_16x16x32_bf16(A1[1], Bcur, zeroC, 0, 0, 0);
        f32x4 a2 = __builtin_amdgcn_mfma_f32_16x16x32_bf16(A1[2], Bcur, zeroC, 0, 0, 0);
        f32x4 a3 = __builtin_amdgcn_mfma_f32_16x16x32_bf16(A1[3], Bcur, zeroC, 0, 0, 0);

        // relu (fmaxf: also NaN-squashing) + bf16 pack: result IS the layer-2
        // B fragment (tau-permuted w2)
        U ba, bb;
        ba.u[0] = cvtpk(fmaxf(a0[0], 0.f), fmaxf(a0[1], 0.f));
        ba.u[1] = cvtpk(fmaxf(a0[2], 0.f), fmaxf(a0[3], 0.f));
        ba.u[2] = cvtpk(fmaxf(a1[0], 0.f), fmaxf(a1[1], 0.f));
        ba.u[3] = cvtpk(fmaxf(a1[2], 0.f), fmaxf(a1[3], 0.f));
        bb.u[0] = cvtpk(fmaxf(a2[0], 0.f), fmaxf(a2[1], 0.f));
        bb.u[1] = cvtpk(fmaxf(a2[2], 0.f), fmaxf(a2[3], 0.f));
        bb.u[2] = cvtpk(fmaxf(a3[0], 0.f), fmaxf(a3[1], 0.f));
        bb.u[3] = cvtpk(fmaxf(a3[2], 0.f), fmaxf(a3[3], 0.f));

        f32x4 o = __builtin_amdgcn_mfma_f32_16x16x32_bf16(A2[0], ba.s, b2f, 0, 0, 0);
        o = __builtin_amdgcn_mfma_f32_16x16x32_bf16(A2[1], bb.s, o, 0, 0, 0);

        if (q < 2) {   // store d (clamped at 0; negatives never beat zeros baseline)
            uint2 ov;
            ov.x = cvtpk(fmaxf(o[0], 0.f), fmaxf(o[1], 0.f));
            ov.y = cvtpk(fmaxf(o[2], 0.f), fmaxf(o[3], 0.f));
            *(uint2*)(dst + (size_t)u * 2048 + j * 128) = ov;
        }
        Bcur = Bnext;
    }
}

// ---------------- gather-max per dest column -> d_out [f][r][c] directly ------
// grid (CDIM/GC, 2); 1024-thread block = 16 waves; wave w owns column c0+w for
// a 128-row half: rows rbase (acc A) and rbase+64 (acc B). Per entry the wave
// reads 2KB contiguous (two back-to-back 1KB wave reads). Runs at ~3.3 TB/s
// of random-2KB L3 traffic -- bracketed ceiling (1KB/2KB contiguity and
// 1/2/3-deep entry pipelines all neutral).
__global__ __launch_bounds__(1024)
void gather_max_t(const unsigned short* __restrict__ dbuf, const int* __restrict__ mergecnt,
                  const int* __restrict__ mergelist, float* __restrict__ out) {
    __shared__ unsigned int ldsP[4][64][20];   // [f/2][rloc][c] packed bf16 pairs
    __shared__ int mlist[GC][MAXL];
    int t = threadIdx.x;
    int w = t >> 6, lane = t & 63;
    int c0 = blockIdx.x * GC;
    int c  = c0 + w;

    int n = mergecnt[c];
    n = n < 0 ? 0 : (n > MAXL ? MAXL : n);        // uniform across the wave
    if (lane < n) {
        int idx = mergelist[(size_t)c * MAXL + lane];
        idx = idx < 0 ? 0 : (idx >= NSETS * MDIM ? NSETS * MDIM - 1 : idx);
        mlist[w][lane] = idx;
    }
    __syncthreads();

    int rbase = blockIdx.y * 128 + lane;
    uint4 accA = make_uint4(0u, 0u, 0u, 0u);
    uint4 accB = make_uint4(0u, 0u, 0u, 0u);
    if (n > 0) {
        const unsigned short* bp = dbuf + ((size_t)mlist[w][0] * RDIM + rbase) * 8;
        uint4 pa = *(const uint4*)(bp);
        uint4 pb = *(const uint4*)(bp + 64 * 8);
        for (int e = 1; e < n; e++) {
            const unsigned short* bq = dbuf + ((size_t)mlist[w][e] * RDIM + rbase) * 8;
            uint4 qa = *(const uint4*)(bq);
            uint4 qb = *(const uint4*)(bq + 64 * 8);
            accA.x = pkmaxu(accA.x, pa.x); accA.y = pkmaxu(accA.y, pa.y);
            accA.z = pkmaxu(accA.z, pa.z); accA.w = pkmaxu(accA.w, pa.w);
            accB.x = pkmaxu(accB.x, pb.x); accB.y = pkmaxu(accB.y, pb.y);
            accB.z = pkmaxu(accB.z, pb.z); accB.w = pkmaxu(accB.w, pb.w);
            pa = qa; pb = qb;
        }
        accA.x = pkmaxu(accA.x, pa.x); accA.y = pkmaxu(accA.y, pa.y);
        accA.z = pkmaxu(accA.z, pa.z); accA.w = pkmaxu(accA.w, pa.w);
        accB.x = pkmaxu(accB.x, pb.x); accB.y = pkmaxu(accB.y, pb.y);
        accB.z = pkmaxu(accB.z, pb.z); accB.w = pkmaxu(accB.w, pb.w);
    }

    // two transpose/write phases (rows rbase.., then rbase+64..)
#pragma unroll
    for (int p = 0; p < 2; p++) {
        if (p) __syncthreads();             // prior read pass done before refill
        uint4 a = p ? accB : accA;
        ldsP[0][lane][w] = a.x;
        ldsP[1][lane][w] = a.y;
        ldsP[2][lane][w] = a.z;
        ldsP[3][lane][w] = a.w;
        __syncthreads();

        // one (f-pair, row, c-quad) per thread: 1024 = 4 * 64 * 4.
        // fmaxf(x,0) is identity on legit values (>=0), squashes NaN/neg.
        int f2 = t >> 8, rl = (t >> 2) & 63, cq = t & 3;
        uint4 v = *(const uint4*)&ldsP[f2][rl][cq * 4];
        float4 lo, hi;
        lo.x = fmaxf(__uint_as_float(v.x << 16), 0.f);
        hi.x = fmaxf(__uint_as_float(v.x & 0xffff0000u), 0.f);
        lo.y = fmaxf(__uint_as_float(v.y << 16), 0.f);
        hi.y = fmaxf(__uint_as_float(v.y & 0xffff0000u), 0.f);
        lo.z = fmaxf(__uint_as_float(v.z << 16), 0.f);
        hi.z = fmaxf(__uint_as_float(v.z & 0xffff0000u), 0.f);
        lo.w = fmaxf(__uint_as_float(v.w << 16), 0.f);
        hi.w = fmaxf(__uint_as_float(v.w & 0xffff0000u), 0.f);
        size_t rowoff = (size_t)blockIdx.y * 128 + p * 64 + rl;
        *(float4*)&out[((size_t)(2 * f2) * RDIM + rowoff) * CDIM + c0 + cq * 4] = lo;
        *(float4*)&out[((size_t)(2 * f2 + 1) * RDIM + rowoff) * CDIM + c0 + cq * 4] = hi;
    }
}

extern "C" void kernel_launch(void* const* d_in, const int* in_sizes, int n_in,
                              void* d_out, int out_size, void* d_ws, size_t ws_size,
                              hipStream_t stream) {
    const float* input = (const float*)d_in[0];
    const float* w1    = (const float*)d_in[1];
    const float* b1    = (const float*)d_in[2];
    const float* w2    = (const float*)d_in[3];
    const float* b2    = (const float*)d_in[4];
    const int*   ind0  = (const int*)d_in[5];
    const int*   ind1  = (const int*)d_in[6];
    const int*   ind2  = (const int*)d_in[7];
    const int*   mix   = (const int*)d_in[8];

    const size_t MiB = 1ull << 20;
    char* ws = (char*)d_ws;
    unsigned short* inT2 = (unsigned short*)ws;                    // 16 MiB
    unsigned short* dbuf = (unsigned short*)(ws + 16 * MiB);       // 48 MiB
    char* tail = ws + 64 * MiB;
    int* inv       = (int*)tail;                                   // 144 KiB
    int* mergecnt  = (int*)(tail + 147456);                        // 16 KiB
    int* mergelist = (int*)(tail + 147456 + 16384);                // 1 MiB
    unsigned short* w1bf = (unsigned short*)(tail + 147456 + 16384 + (size_t)CDIM * MAXL * 4);
    unsigned short* w2bf = w1bf + 64 * 32;

    hipMemsetAsync(mergecnt, 0, CDIM * sizeof(int), stream);       // graph-capturable
    setup1<<<PREPB + 144, 256, 0, stream>>>(input, inT2, ind0, ind1, ind2,
                                            w1, b1, w2, inv, w1bf, w2bf);
    mlp_store<<<MLPB + 144, 256, 0, stream>>>(inT2, w1bf, w2bf, b2,
                                              ind0, ind1, ind2, mix, inv, dbuf,
                                              mergecnt, mergelist);
    gather_max_t<<<dim3(CDIM / GC, 2), 1024, 0, stream>>>(dbuf, mergecnt, mergelist,
                                                          (float*)d_out);
}